// Round 12
// baseline (318.540 us; speedup 1.0000x reference)
//
#include <hip/hip_runtime.h>
#include <stdint.h>

// ---------------------------------------------------------------------------
// LogSparse attention (B=4, T=2048, E=512, H=8, head_dim=64, q/k width e=512)
//   0) convert x, w_qk to bf16; transpose+convert w_v, w_proj to [N][K] bf16
//   1) QK = x @ w_qk^T           (bf16 MFMA GEMM, C bf16 [8192][8192])
//   2) V  = x @ w_v + b_v        (bf16 MFMA GEMM, stored transposed [b,h,d,t])
//   3) flash attention -> ctx bf16: 512 UNIFORM blocks (paired q-tiles
//      31-p and p = 33 ktiles), 4 waves 2x2 (32 rows x 32 keys),
//      K: 3 x 16KB chunk buffers [64k x 128e], staged 2 ahead with COUNTED
//      vmcnt (4 / 12 at chunk%4==3) + raw s_barrier -- no vmcnt(0) drains.
//      no-max softmax, Plds stride-40, per-wave partial O/l combined in LDS.
//   4) out = ctx @ w_proj + b_proj (f32 out)
// ---------------------------------------------------------------------------

typedef __attribute__((ext_vector_type(8))) short short8;
typedef __attribute__((ext_vector_type(4))) float f32x4;
typedef __attribute__((ext_vector_type(4))) unsigned short us4;

__device__ __forceinline__ f32x4 fzero4() { f32x4 z = {0.f, 0.f, 0.f, 0.f}; return z; }

__device__ __forceinline__ unsigned short f2bf(float f) {  // RNE f32->bf16
  unsigned u = __float_as_uint(f);
  u += 0x7fff + ((u >> 16) & 1);
  return (unsigned short)(u >> 16);
}

__device__ __forceinline__ void gload_lds16(const void* g, void* l) {
  __builtin_amdgcn_global_load_lds((const __attribute__((address_space(1))) void*)g,
                                   (__attribute__((address_space(3))) void*)l, 16, 0, 0);
}

// bijective XCD swizzle (nwg % 8 == 0 for all our grids)
__device__ __forceinline__ int xcd_swizzle(int flat, int nwg) {
  const int cpx = nwg >> 3;
  return (flat & 7) * cpx + (flat >> 3);
}

// ---------------------------------------------------------------------------
// GEMM: C[M,N] = A[M,K] * B[N,K]^T  (A,B bf16 row-major, K-contiguous)
// 128x128 tile, BK=32, 256 threads (4 waves, 2x2), 16x16x32 bf16 MFMA.
// EPI 0: C bf16 row-major, no bias
// EPI 1: V epilogue: bf16, +bias, stored transposed V_t[(b*512+col)][t]
// EPI 2: C f32 row-major, +bias
// ---------------------------------------------------------------------------
template <int EPI>
__global__ __launch_bounds__(256, 2) void gemm_bt(const unsigned short* __restrict__ A,
                                                  const unsigned short* __restrict__ B,
                                                  void* __restrict__ Cout,
                                                  const float* __restrict__ bias,
                                                  int M, int N, int K) {
  __shared__ unsigned short As[128 * 32];
  __shared__ unsigned short Bs[128 * 32];
  const int tid = threadIdx.x;
  const int wid = tid >> 6;
  const int lane = tid & 63;
  const int wm = wid >> 1, wn = wid & 1;
  const int nbx = (M + 127) / 128;
  const int sw = xcd_swizzle(blockIdx.y * gridDim.x + blockIdx.x, gridDim.x * gridDim.y);
  const long m0 = (long)(sw % nbx) * 128;
  const long n0 = (long)(sw / nbx) * 128;

  f32x4 acc[4][4];
#pragma unroll
  for (int i = 0; i < 4; ++i)
#pragma unroll
    for (int j = 0; j < 4; ++j) acc[i][j] = fzero4();

  const int lrow = tid >> 2;          // 0..63
  const int lcol = (tid & 3) * 8;     // 0,8,16,24
  const unsigned short* Ag = A + (m0 + lrow) * (long)K + lcol;
  const unsigned short* Bg = B + (n0 + lrow) * (long)K + lcol;
  unsigned short* Asl = As + tid * 8;
  unsigned short* Bsl = Bs + tid * 8;
  const long K64 = (long)64 * K;

  const int fr = lane & 15;
  const int fk = (lane >> 4) * 8;

  for (int k0 = 0; k0 < K; k0 += 32) {
    gload_lds16(Ag + k0, Asl);
    gload_lds16(Ag + K64 + k0, Asl + 2048);
    gload_lds16(Bg + k0, Bsl);
    gload_lds16(Bg + K64 + k0, Bsl + 2048);
    __syncthreads();
    short8 af[4], bfr[4];
#pragma unroll
    for (int i = 0; i < 4; ++i) af[i] = *(const short8*)&As[(wm * 64 + i * 16 + fr) * 32 + fk];
#pragma unroll
    for (int j = 0; j < 4; ++j) bfr[j] = *(const short8*)&Bs[(wn * 64 + j * 16 + fr) * 32 + fk];
#pragma unroll
    for (int i = 0; i < 4; ++i)
#pragma unroll
      for (int j = 0; j < 4; ++j)
        acc[i][j] = __builtin_amdgcn_mfma_f32_16x16x32_bf16(af[i], bfr[j], acc[i][j], 0, 0, 0);
    __syncthreads();
  }

  const int fg = lane >> 4;
#pragma unroll
  for (int i = 0; i < 4; ++i) {
#pragma unroll
    for (int j = 0; j < 4; ++j) {
      const long row0 = m0 + wm * 64 + i * 16 + fg * 4;  // +r
      const long col = n0 + wn * 64 + j * 16 + fr;
      if (EPI == 0) {
        unsigned short* C = (unsigned short*)Cout;
#pragma unroll
        for (int r = 0; r < 4; ++r) C[(row0 + r) * (long)N + col] = f2bf(acc[i][j][r]);
      } else if (EPI == 1) {
        unsigned short* C = (unsigned short*)Cout;
        const float bs = bias[col];
        const int b_ = (int)(row0 >> 11);
        const int t0 = (int)(row0 & 2047);
        us4 pk;
#pragma unroll
        for (int r = 0; r < 4; ++r) pk[r] = f2bf(acc[i][j][r] + bs);
        *(us4*)&C[((size_t)(b_ * 512 + col)) * 2048 + t0] = pk;  // [b,h,d][t]
      } else {
        float* C = (float*)Cout;
        const float bs = bias[col];
#pragma unroll
        for (int r = 0; r < 4; ++r) C[(row0 + r) * (long)N + col] = acc[i][j][r] + bs;
      }
    }
  }
}

// ---------------------------------------------------------------------------
// Flash attention. 512 uniform blocks, 256 threads (4 waves, 2x2 split).
// Block id -> xcd = id&7, bh = xcd*4 + ((id>>3)&3), p = id>>5.
// Processes q-tiles (31-p) then (p): 33 ktiles total per block (uniform).
// Wave (wm,wn): q-rows wm*32..+31 (2 i-groups), keys wn*32..+31 (2 j).
// K pipeline: 3 chunk buffers, stage chunk g+2 at top of chunk g, counted
// s_waitcnt vmcnt(4) (or 12 at g%4==3 where V(8)+stage(4) are younger),
// raw s_barrier -- staging latency spans 2 full chunk phases.
// V: plain loads at g%4==2 (compiler-inserted wait before PV).
// No-max softmax; Plds stride 40; per-wave partial O/l, LDS combine per tile.
// ---------------------------------------------------------------------------
#define STAGE(BUF, G)                                                           \
  do {                                                                          \
    const unsigned short* _src =                                                \
        Kg + (size_t)((G) >> 2) * (64 * 8192) + ((G) & 3) * 128;                \
    unsigned short* _dst = &Kb[(BUF) * 8192 + tid * 8];                         \
    _Pragma("unroll") for (int _r = 0; _r < 4; ++_r)                            \
        gload_lds16(_src + (size_t)_r * 16 * 8192, _dst + _r * 2048);           \
  } while (0)

#define QK_QTR(BUF, C)                                                          \
  __builtin_amdgcn_s_setprio(1);                                                \
  _Pragma("unroll") for (int e = 0; e < 4; ++e) {                               \
    _Pragma("unroll") for (int j = 0; j < 2; ++j) {                             \
      const int _row = wn * 32 + j * 16 + fr;                                   \
      const short8 bfr = *(const short8*)&Kb[(BUF) * 8192 + _row * 128 +        \
                                             (((e * 4 + fg) ^ xsw) << 3)];      \
      s[0][j] = __builtin_amdgcn_mfma_f32_16x16x32_bf16(qreg[0][(C) * 4 + e],   \
                                                        bfr, s[0][j], 0, 0, 0); \
      s[1][j] = __builtin_amdgcn_mfma_f32_16x16x32_bf16(qreg[1][(C) * 4 + e],   \
                                                        bfr, s[1][j], 0, 0, 0); \
    }                                                                           \
  }                                                                             \
  __builtin_amdgcn_s_setprio(0);

__global__ __launch_bounds__(256, 2) void flash_attn(const unsigned short* __restrict__ QK,
                                                     const unsigned short* __restrict__ Vt,
                                                     unsigned short* __restrict__ ctx) {
  __shared__ unsigned short Kb[3 * 64 * 128];  // 3 x 16 KB chunk buffers
  __shared__ unsigned short Plds[4][16 * 40];  // 1.25 KB per wave (padded)

  const int tid = threadIdx.x, wid = tid >> 6, lane = tid & 63;
  const int fr = lane & 15, fg = lane >> 4;
  const int xsw = fr & 7;
  const int wm = wid >> 1, wn = wid & 1;

  const int id = blockIdx.x;
  const int bh = (id & 7) * 4 + ((id >> 3) & 3);  // 4 bh per XCD (K L2 locality)
  const int p = id >> 5;                          // 0..15
  const int b = bh >> 3, h = bh & 7;

  // K staging base (pre-swizzled global source; LDS dest linear).
  // chunk [64 keys][128 e]: round r covers keys r*16 + (tid>>4); slot tid&15.
  const int gslot = (tid & 15) ^ ((tid >> 4) & 7);
  const unsigned short* Kg =
      QK + (size_t)(b * 2048 + (tid >> 4)) * 8192 + 4096 + h * 512 + gslot * 8;

  short8 ones;
#pragma unroll
  for (int z = 0; z < 8; ++z) ones[z] = (short)0x3F80;  // bf16 1.0

  float* Osc = (float*)&Kb[0];     // combine scratch (16 KB), reused
  float* lsc = (float*)&Kb[8192];  // 256 B

  for (int tile = 0; tile < 2; ++tile) {
    const int qt = (tile == 0) ? (31 - p) : p;
    const int NG = (qt + 1) * 4;  // chunks in this tile

    // ---- Q fragments: rows qt*64 + wm*32 + {i*16} + fr, 16 e-steps (128 VGPR)
    short8 qreg[2][16];
    {
      const unsigned short* qp =
          QK + (size_t)(b * 2048 + qt * 64 + wm * 32 + fr) * 8192 + h * 512 + fg * 8;
#pragma unroll
      for (int i = 0; i < 2; ++i)
#pragma unroll
        for (int e = 0; e < 16; ++e)
          qreg[i][e] = *(const short8*)(qp + (size_t)i * 16 * 8192 + e * 32);
    }

    // ---- mask bitmaps, bit r*2+j (8 bits), cols c = wn*32 + j*16 + fr
    unsigned m_gen[2], m_t0[2], m_diag[2];
#pragma unroll
    for (int i = 0; i < 2; ++i) {
      const int lrow = wm * 32 + i * 16 + fg * 4;  // row within 64-row tile
      m_gen[i] = 0xFFu; m_t0[i] = 0xFFu; m_diag[i] = 0u;
      if (qt <= 5) {  // global rows < 384: plain causal
#pragma unroll
        for (int r = 0; r < 4; ++r)
#pragma unroll
          for (int j = 0; j < 2; ++j)
            if (wn * 32 + j * 16 + fr <= lrow + r) m_diag[i] |= 1u << (r * 2 + j);
      } else {
        m_gen[i] = 0; m_t0[i] = 0;
        const unsigned long long SBITS = 0x20002022FFull;  // t in {0..7,9,13,21,37}
#pragma unroll
        for (int r = 0; r < 4; ++r) {
          const int irow = qt * 64 + lrow + r;
#pragma unroll
          for (int j = 0; j < 2; ++j) {
            const int c = wn * 32 + j * 16 + fr;
            const int t = (irow - c) & 63;
            const unsigned g = (unsigned)((SBITS >> t) & 1ull);
            const unsigned bit = 1u << (r * 2 + j);
            if (g) m_gen[i] |= bit;
            if ((c + t >= 5) ? (g != 0) : (t >= 1)) m_t0[i] |= bit;  // terminal rule
            if (g && c <= lrow + r) m_diag[i] |= bit;
          }
        }
      }
    }

    f32x4 o[2][4], ol[2];
#pragma unroll
    for (int i = 0; i < 2; ++i) {
      ol[i] = fzero4();
#pragma unroll
      for (int j = 0; j < 4; ++j) o[i][j] = fzero4();
    }

    // prologue: chunks 0,1 -> buffers 0,1 (stage depth 2)
    STAGE(0, 0);
    STAGE(1, 1);
    int rb = 0;  // buffer holding chunk g
    int sb = 2;  // buffer receiving chunk g+2

    for (int kt = 0; kt <= qt; ++kt) {
      f32x4 s[2][2];
#pragma unroll
      for (int i = 0; i < 2; ++i)
#pragma unroll
        for (int j = 0; j < 2; ++j) s[i][j] = fzero4();
      short8 vreg[4];

#pragma unroll
      for (int c = 0; c < 4; ++c) {
        // counted wait: retire exactly chunk g's 4 stage-loads.
        // at c==3 the younger ops are V(8, issued at c==2) + stage(4) = 12.
        if (c == 3) {
          asm volatile("s_waitcnt vmcnt(12)" ::: "memory");
        } else {
          asm volatile("s_waitcnt vmcnt(4)" ::: "memory");
        }
        asm volatile("s_barrier" ::: "memory");
        {
          int g2 = kt * 4 + c + 2;
          if (g2 >= NG) g2 = NG - 1;  // tail dummy keeps counts uniform
          STAGE(sb, g2);
        }
        if (c == 2) {  // V fragments; compiler inserts the wait before PV
#pragma unroll
          for (int jd = 0; jd < 4; ++jd)
            vreg[jd] = *(const short8*)(Vt + (size_t)(bh * 64 + jd * 16 + fr) * 2048 +
                                        kt * 64 + wn * 32 + fg * 8);
        }
        QK_QTR(rb, c);
        rb = (rb == 2) ? 0 : rb + 1;
        sb = (sb == 2) ? 0 : sb + 1;
      }

      // ---- per i-group: no-max softmax -> Plds (padded) -> PV
#pragma unroll
      for (int i = 0; i < 2; ++i) {
        unsigned mm = (kt == 0) ? m_t0[i] : m_gen[i];
        if (kt == qt) mm &= m_diag[i];
#pragma unroll
        for (int r = 0; r < 4; ++r) {
#pragma unroll
          for (int j = 0; j < 2; ++j) {
            float v = s[i][j][r] * 0.18033688f;  // 0.125 * log2(e)
            v = ((mm >> (r * 2 + j)) & 1u) ? v : -1e30f;
            const float pv = __builtin_amdgcn_exp2f(v);
            Plds[wid][(fg * 4 + r) * 40 + j * 16 + fr] = f2bf(pv);
          }
        }
        __builtin_amdgcn_s_setprio(1);
        const short8 pa = *(const short8*)&Plds[wid][fr * 40 + fg * 8];
#pragma unroll
        for (int jd = 0; jd < 4; ++jd)
          o[i][jd] = __builtin_amdgcn_mfma_f32_16x16x32_bf16(pa, vreg[jd], o[i][jd], 0, 0, 0);
        ol[i] = __builtin_amdgcn_mfma_f32_16x16x32_bf16(pa, ones, ol[i], 0, 0, 0);
        __builtin_amdgcn_s_setprio(0);
      }
    }

    // ---- combine wn=0 + wn=1 partials via LDS; normalize; write ctx
    __syncthreads();  // full drain (incl. dangling dummy stages); Kb -> scratch
    if (wn == 1) {
#pragma unroll
      for (int i = 0; i < 2; ++i) {
#pragma unroll
        for (int r = 0; r < 4; ++r) {
          const int row32 = wm * 32 + i * 16 + fg * 4 + r;
#pragma unroll
          for (int jd = 0; jd < 4; ++jd)
            Osc[row32 * 64 + jd * 16 + fr] = o[i][jd][r];
          if (fr == 0) lsc[row32] = ol[i][r];
        }
      }
    }
    __syncthreads();
    if (wn == 0) {
#pragma unroll
      for (int i = 0; i < 2; ++i) {
#pragma unroll
        for (int r = 0; r < 4; ++r) {
          const int row32 = wm * 32 + i * 16 + fg * 4 + r;
          const float l = ol[i][r] + lsc[row32];
          const float inv = 1.0f / l;
          unsigned short* cp =
              ctx + (size_t)(b * 2048 + qt * 64 + row32) * 512 + h * 64;
#pragma unroll
          for (int jd = 0; jd < 4; ++jd) {
            const float v = o[i][jd][r] + Osc[row32 * 64 + jd * 16 + fr];
            cp[jd * 16 + fr] = f2bf(v * inv);
          }
        }
      }
    }
    __syncthreads();  // scratch reads done before next tile's staging
  }
}

// ---------------------------------------------------------------------------
// Conversions
// ---------------------------------------------------------------------------
__global__ void f32_to_bf16_k(const float* __restrict__ in, unsigned short* __restrict__ out,
                              int n4) {
  const int i = blockIdx.x * 256 + threadIdx.x;
  if (i < n4) {
    const float4 v = ((const float4*)in)[i];
    us4 o;
    o[0] = f2bf(v.x);
    o[1] = f2bf(v.y);
    o[2] = f2bf(v.z);
    o[3] = f2bf(v.w);
    ((us4*)out)[i] = o;
  }
}

// out[n][k] = bf16(in[k][n]) for 512x512 weight (x @ W -> C = A * W^T form)
__global__ void transpose_w_k(const float* __restrict__ in, unsigned short* __restrict__ out) {
  const int idx = blockIdx.x * 256 + threadIdx.x;
  const int row = idx >> 9, col = idx & 511;
  out[idx] = f2bf(in[col * 512 + row]);
}

// ---------------------------------------------------------------------------
extern "C" void kernel_launch(void* const* d_in, const int* in_sizes, int n_in,
                              void* d_out, int out_size, void* d_ws, size_t ws_size,
                              hipStream_t stream) {
  (void)in_sizes; (void)n_in; (void)out_size; (void)ws_size;
  const float* x = (const float*)d_in[0];
  const float* wqk = (const float*)d_in[1];
  const float* wv = (const float*)d_in[2];
  const float* bv = (const float*)d_in[3];
  const float* wp = (const float*)d_in[4];
  const float* bp = (const float*)d_in[5];
  // d_in[6] (mask) unused: mask computed analytically in-kernel.

  char* ws = (char*)d_ws;
  unsigned short* x_bf   = (unsigned short*)(ws + 0);                    //   8 MB [8192][512]
  unsigned short* wqk_bf = (unsigned short*)(ws + (size_t)8 * 1048576);  //   8 MB [8192][512]
  unsigned short* wv_t   = (unsigned short*)(ws + (size_t)16 * 1048576); // 0.5 MB [512][512]
  unsigned short* wp_t   = (unsigned short*)(ws + (size_t)17 * 1048576); // 0.5 MB [512][512]
  unsigned short* qk_bf  = (unsigned short*)(ws + (size_t)18 * 1048576); // 128 MB [8192][8192]
  unsigned short* v_t    = (unsigned short*)(ws + (size_t)146 * 1048576);//   8 MB [2048][2048]
  unsigned short* ctx_bf = (unsigned short*)(ws + (size_t)154 * 1048576);//   8 MB [8192][512]

  f32_to_bf16_k<<<4096, 256, 0, stream>>>(x, x_bf, 1048576);
  f32_to_bf16_k<<<4096, 256, 0, stream>>>(wqk, wqk_bf, 1048576);
  transpose_w_k<<<1024, 256, 0, stream>>>(wv, wv_t);
  transpose_w_k<<<1024, 256, 0, stream>>>(wp, wp_t);

  // QK = x @ w_qk^T : [8192][8192] bf16 (cols 0..4095 = Q, 4096..8191 = K)
  gemm_bt<0><<<dim3(64, 64), 256, 0, stream>>>(x_bf, wqk_bf, qk_bf, nullptr, 8192, 8192, 512);
  // V = x @ w_v + b_v, stored transposed [ (b*8+h)*64+d ][ t ]
  gemm_bt<1><<<dim3(64, 4), 256, 0, stream>>>(x_bf, wv_t, v_t, bv, 8192, 512, 512);

  flash_attn<<<512, 256, 0, stream>>>(qk_bf, v_t, ctx_bf);

  // out = ctx @ w_proj + b_proj (f32)
  gemm_bt<2><<<dim3(64, 4), 256, 0, stream>>>(ctx_bf, wp_t, d_out, bp, 8192, 512, 512);
}

// Round 13
// 275.141 us; speedup vs baseline: 1.1577x; 1.1577x over previous
//
#include <hip/hip_runtime.h>
#include <stdint.h>

// ---------------------------------------------------------------------------
// LogSparse attention (B=4, T=2048, E=512, H=8, head_dim=64, q/k width e=512)
//   0) convert x, w_qk to bf16; transpose+convert w_v, w_proj to [N][K] bf16
//   1) QK = x @ w_qk^T   (256^2-tile 8-wave bf16 MFMA GEMM, counted vmcnt)
//   2) V  = x @ w_v + b_v (128^2 GEMM, stored transposed [b,h,d,t])
//   3) flash attention -> ctx bf16 (R9 structure: 512 uniform blocks,
//      2x2 wave split, dbuf 64x256 K chunks + syncthreads, no-max softmax)
//   4) out = ctx @ w_proj + b_proj (f32, 128^2 GEMM)
// ---------------------------------------------------------------------------

typedef __attribute__((ext_vector_type(8))) short short8;
typedef __attribute__((ext_vector_type(4))) float f32x4;
typedef __attribute__((ext_vector_type(4))) unsigned short us4;

__device__ __forceinline__ f32x4 fzero4() { f32x4 z = {0.f, 0.f, 0.f, 0.f}; return z; }

__device__ __forceinline__ unsigned short f2bf(float f) {  // RNE f32->bf16
  unsigned u = __float_as_uint(f);
  u += 0x7fff + ((u >> 16) & 1);
  return (unsigned short)(u >> 16);
}

__device__ __forceinline__ void gload_lds16(const void* g, void* l) {
  __builtin_amdgcn_global_load_lds((const __attribute__((address_space(1))) void*)g,
                                   (__attribute__((address_space(3))) void*)l, 16, 0, 0);
}

// bijective XCD swizzle (nwg % 8 == 0 for all our grids)
__device__ __forceinline__ int xcd_swizzle(int flat, int nwg) {
  const int cpx = nwg >> 3;
  return (flat & 7) * cpx + (flat >> 3);
}

// ---------------------------------------------------------------------------
// QK GEMM: C[8192,8192] = A[8192,512] * B[8192,512]^T, bf16 out.
// 256x256 tile, BK=64, 512 threads = 8 waves (2M x 4N), 1 block/CU (128KB LDS).
// Per iter: issue next full-tile stage (8 gload_lds) -> vmcnt(8) -> barrier ->
// ds_reads + 64 MFMA/wave -> barrier. Stage cover = one full iteration.
// LDS slot-XOR swizzle via pre-swizzled global source (read is 2-way free).
// ---------------------------------------------------------------------------
#define STAGE256(D, KT)                                                            \
  do {                                                                             \
    _Pragma("unroll") for (int l = 0; l < 4; ++l) {                                \
      gload_lds16(Ab + (size_t)l * 32768 + (KT) * 64, &S[D][0][l * 4096 + tid * 8]); \
      gload_lds16(Bb + (size_t)l * 32768 + (KT) * 64, &S[D][1][l * 4096 + tid * 8]); \
    }                                                                              \
  } while (0)

__global__ __launch_bounds__(512, 2) void gemm256(const unsigned short* __restrict__ A,
                                                  const unsigned short* __restrict__ B,
                                                  unsigned short* __restrict__ C) {
  __shared__ unsigned short S[2][2][16384];  // [dbuf][A/B][256 rows x 64 k] = 128 KB

  const int tid = threadIdx.x;
  const int wid = tid >> 6, lane = tid & 63;
  const int fr = lane & 15, fg = lane >> 4;
  const int wm = wid >> 2, wn = wid & 3;

  const int sw = xcd_swizzle(blockIdx.x, 1024);
  const long m0 = (long)(sw & 31) * 256;
  const long n0 = (long)(sw >> 5) * 256;

  // staging source: thread covers rows (tid>>3) + l*64, 16B slot (tid&7),
  // pre-swizzled: global slot = (tid&7) ^ ((tid>>3)&7); LDS dest linear.
  const int gslot = (tid & 7) ^ ((tid >> 3) & 7);
  const unsigned short* Ab = A + (m0 + (tid >> 3)) * 512 + gslot * 8;
  const unsigned short* Bb = B + (n0 + (tid >> 3)) * 512 + gslot * 8;

  f32x4 acc[8][4];
#pragma unroll
  for (int i = 0; i < 8; ++i)
#pragma unroll
    for (int j = 0; j < 4; ++j) acc[i][j] = fzero4();

  STAGE256(0, 0);  // prologue

  const int xsw = fr & 7;
  for (int kt = 0; kt < 8; ++kt) {
    const int d = kt & 1;
    if (kt < 7) {
      STAGE256(d ^ 1, kt + 1);  // issue next stage BEFORE the wait
      asm volatile("s_waitcnt vmcnt(8)" ::: "memory");  // retire stage(kt)
    } else {
      asm volatile("s_waitcnt vmcnt(0)" ::: "memory");
    }
    __builtin_amdgcn_s_barrier();

    short8 bfr[4][2];
#pragma unroll
    for (int nf = 0; nf < 4; ++nf)
#pragma unroll
      for (int ks = 0; ks < 2; ++ks)
        bfr[nf][ks] = *(const short8*)&S[d][1][(wn * 64 + nf * 16 + fr) * 64 +
                                               (((ks * 4 + fg) ^ xsw) << 3)];
#pragma unroll
    for (int mh = 0; mh < 2; ++mh) {
      short8 af[4][2];
#pragma unroll
      for (int mf = 0; mf < 4; ++mf)
#pragma unroll
        for (int ks = 0; ks < 2; ++ks)
          af[mf][ks] = *(const short8*)&S[d][0][(wm * 128 + mh * 64 + mf * 16 + fr) * 64 +
                                                (((ks * 4 + fg) ^ xsw) << 3)];
      __builtin_amdgcn_s_setprio(1);
#pragma unroll
      for (int mf = 0; mf < 4; ++mf)
#pragma unroll
        for (int nf = 0; nf < 4; ++nf)
#pragma unroll
          for (int ks = 0; ks < 2; ++ks)
            acc[mh * 4 + mf][nf] = __builtin_amdgcn_mfma_f32_16x16x32_bf16(
                af[mf][ks], bfr[nf][ks], acc[mh * 4 + mf][nf], 0, 0, 0);
      __builtin_amdgcn_s_setprio(0);
    }
    __builtin_amdgcn_s_barrier();  // reads done before next iter overwrites d^1
  }

  // epilogue: C[row][col] bf16
#pragma unroll
  for (int mf = 0; mf < 8; ++mf) {
#pragma unroll
    for (int nf = 0; nf < 4; ++nf) {
      const long row0 = m0 + wm * 128 + mf * 16 + fg * 4;
      const long col = n0 + wn * 64 + nf * 16 + fr;
#pragma unroll
      for (int r = 0; r < 4; ++r) C[(row0 + r) * 8192 + col] = f2bf(acc[mf][nf][r]);
    }
  }
}

// ---------------------------------------------------------------------------
// GEMM: C[M,N] = A[M,K] * B[N,K]^T  (A,B bf16 row-major, K-contiguous)
// 128x128 tile, BK=32, 256 threads (4 waves, 2x2), 16x16x32 bf16 MFMA.
// EPI 1: V epilogue: bf16, +bias, stored transposed V_t[(b*512+col)][t]
// EPI 2: C f32 row-major, +bias
// ---------------------------------------------------------------------------
template <int EPI>
__global__ __launch_bounds__(256, 2) void gemm_bt(const unsigned short* __restrict__ A,
                                                  const unsigned short* __restrict__ B,
                                                  void* __restrict__ Cout,
                                                  const float* __restrict__ bias,
                                                  int M, int N, int K) {
  __shared__ unsigned short As[128 * 32];
  __shared__ unsigned short Bs[128 * 32];
  const int tid = threadIdx.x;
  const int wid = tid >> 6;
  const int lane = tid & 63;
  const int wm = wid >> 1, wn = wid & 1;
  const int nbx = (M + 127) / 128;
  const int sw = xcd_swizzle(blockIdx.y * gridDim.x + blockIdx.x, gridDim.x * gridDim.y);
  const long m0 = (long)(sw % nbx) * 128;
  const long n0 = (long)(sw / nbx) * 128;

  f32x4 acc[4][4];
#pragma unroll
  for (int i = 0; i < 4; ++i)
#pragma unroll
    for (int j = 0; j < 4; ++j) acc[i][j] = fzero4();

  const int lrow = tid >> 2;          // 0..63
  const int lcol = (tid & 3) * 8;     // 0,8,16,24
  const unsigned short* Ag = A + (m0 + lrow) * (long)K + lcol;
  const unsigned short* Bg = B + (n0 + lrow) * (long)K + lcol;
  unsigned short* Asl = As + tid * 8;
  unsigned short* Bsl = Bs + tid * 8;
  const long K64 = (long)64 * K;

  const int fr = lane & 15;
  const int fk = (lane >> 4) * 8;

  for (int k0 = 0; k0 < K; k0 += 32) {
    gload_lds16(Ag + k0, Asl);
    gload_lds16(Ag + K64 + k0, Asl + 2048);
    gload_lds16(Bg + k0, Bsl);
    gload_lds16(Bg + K64 + k0, Bsl + 2048);
    __syncthreads();
    short8 af[4], bfr[4];
#pragma unroll
    for (int i = 0; i < 4; ++i) af[i] = *(const short8*)&As[(wm * 64 + i * 16 + fr) * 32 + fk];
#pragma unroll
    for (int j = 0; j < 4; ++j) bfr[j] = *(const short8*)&Bs[(wn * 64 + j * 16 + fr) * 32 + fk];
#pragma unroll
    for (int i = 0; i < 4; ++i)
#pragma unroll
      for (int j = 0; j < 4; ++j)
        acc[i][j] = __builtin_amdgcn_mfma_f32_16x16x32_bf16(af[i], bfr[j], acc[i][j], 0, 0, 0);
    __syncthreads();
  }

  const int fg = lane >> 4;
#pragma unroll
  for (int i = 0; i < 4; ++i) {
#pragma unroll
    for (int j = 0; j < 4; ++j) {
      const long row0 = m0 + wm * 64 + i * 16 + fg * 4;  // +r
      const long col = n0 + wn * 64 + j * 16 + fr;
      if (EPI == 1) {
        unsigned short* C = (unsigned short*)Cout;
        const float bs = bias[col];
        const int b_ = (int)(row0 >> 11);
        const int t0 = (int)(row0 & 2047);
        us4 pk;
#pragma unroll
        for (int r = 0; r < 4; ++r) pk[r] = f2bf(acc[i][j][r] + bs);
        *(us4*)&C[((size_t)(b_ * 512 + col)) * 2048 + t0] = pk;  // [b,h,d][t]
      } else {
        float* C = (float*)Cout;
        const float bs = bias[col];
#pragma unroll
        for (int r = 0; r < 4; ++r) C[(row0 + r) * (long)N + col] = acc[i][j][r] + bs;
      }
    }
  }
}

// ---------------------------------------------------------------------------
// Flash attention (R9 structure, 162 us verified). 512 uniform blocks,
// 256 threads (4 waves, 2x2 split). Block id -> xcd = id&7,
// bh = xcd*4 + ((id>>3)&3), p = id>>5. Processes q-tiles (31-p) then (p):
// 33 ktiles per block (uniform). Wave (wm,wn): q-rows wm*32..+31,
// keys wn*32..+31. K: dbuf [64 keys][256 e] chunks + syncthreads.
// V: global->reg. P: wave-private swizzled LDS. No-max softmax ->
// per-wave partial O,l; one LDS combine per tile.
// ---------------------------------------------------------------------------
#define STAGE(BUF, G)                                                          \
  do {                                                                         \
    const int _kt = (G) >> 1, _hf = (G) & 1;                                   \
    const unsigned short* _src = Kg + (size_t)(_kt) * (64 * 8192) + _hf * 256; \
    _Pragma("unroll") for (int _r = 0; _r < 8; ++_r)                           \
        gload_lds16(_src + (size_t)_r * 8 * 8192, &Kb[BUF][_r * 2048 + tid * 8]); \
  } while (0)

#define QK_HALF(BUF, HF)                                                       \
  __builtin_amdgcn_s_setprio(1);                                               \
  _Pragma("unroll") for (int e8 = 0; e8 < 8; ++e8) {                           \
    _Pragma("unroll") for (int j = 0; j < 2; ++j) {                            \
      const int _row = wn * 32 + j * 16 + fr;                                  \
      const short8 bfr = *(const short8*)&Kb[BUF][_row * 256 +                 \
                                                  (((e8 * 4 + fg) ^ xsw) << 3)]; \
      s[0][j] = __builtin_amdgcn_mfma_f32_16x16x32_bf16(qreg[0][(HF)*8 + e8],  \
                                                        bfr, s[0][j], 0, 0, 0); \
      s[1][j] = __builtin_amdgcn_mfma_f32_16x16x32_bf16(qreg[1][(HF)*8 + e8],  \
                                                        bfr, s[1][j], 0, 0, 0); \
    }                                                                          \
  }                                                                            \
  __builtin_amdgcn_s_setprio(0);

__global__ __launch_bounds__(256, 2) void flash_attn(const unsigned short* __restrict__ QK,
                                                     const unsigned short* __restrict__ Vt,
                                                     unsigned short* __restrict__ ctx) {
  __shared__ unsigned short Kb[2][64 * 256];   // 2 x 32 KB (dbuf K chunks)
  __shared__ unsigned short Plds[4][32 * 32];  // 2 KB per wave

  const int tid = threadIdx.x, wid = tid >> 6, lane = tid & 63;
  const int fr = lane & 15, fg = lane >> 4;
  const int xsw = fr & 7;
  const int wm = wid >> 1, wn = wid & 1;

  const int id = blockIdx.x;
  const int bh = (id & 7) * 4 + ((id >> 3) & 3);  // 4 bh per XCD (K L2 locality)
  const int p = id >> 5;                          // 0..15
  const int b = bh >> 3, h = bh & 7;

  // K staging base (pre-swizzled global source; LDS dest linear).
  const int gslot = (tid & 31) ^ (tid >> 5);
  const unsigned short* Kg =
      QK + (size_t)(b * 2048 + (tid >> 5)) * 8192 + 4096 + h * 512 + gslot * 8;

  short8 ones;
#pragma unroll
  for (int z = 0; z < 8; ++z) ones[z] = (short)0x3F80;  // bf16 1.0

  float* Osc = (float*)&Kb[0][0];    // combine scratch (16 KB), reused
  float* lsc = (float*)&Kb[1][0];    // 256 B

  for (int tile = 0; tile < 2; ++tile) {
    const int qt = (tile == 0) ? (31 - p) : p;

    // ---- Q fragments: rows qt*64 + wm*32 + {i*16} + fr, 16 e-steps (128 VGPR)
    short8 qreg[2][16];
    {
      const unsigned short* qp =
          QK + (size_t)(b * 2048 + qt * 64 + wm * 32 + fr) * 8192 + h * 512 + fg * 8;
#pragma unroll
      for (int i = 0; i < 2; ++i)
#pragma unroll
        for (int e = 0; e < 16; ++e)
          qreg[i][e] = *(const short8*)(qp + (size_t)i * 16 * 8192 + e * 32);
    }

    // ---- mask bitmaps, bit r*2+j (8 bits), cols c = wn*32 + j*16 + fr
    unsigned m_gen[2], m_t0[2], m_diag[2];
#pragma unroll
    for (int i = 0; i < 2; ++i) {
      const int lrow = wm * 32 + i * 16 + fg * 4;  // row within 64-row tile
      m_gen[i] = 0xFFu; m_t0[i] = 0xFFu; m_diag[i] = 0u;
      if (qt <= 5) {  // global rows < 384: plain causal
#pragma unroll
        for (int r = 0; r < 4; ++r)
#pragma unroll
          for (int j = 0; j < 2; ++j)
            if (wn * 32 + j * 16 + fr <= lrow + r) m_diag[i] |= 1u << (r * 2 + j);
      } else {
        m_gen[i] = 0; m_t0[i] = 0;
        const unsigned long long SBITS = 0x20002022FFull;  // t in {0..7,9,13,21,37}
#pragma unroll
        for (int r = 0; r < 4; ++r) {
          const int irow = qt * 64 + lrow + r;
#pragma unroll
          for (int j = 0; j < 2; ++j) {
            const int c = wn * 32 + j * 16 + fr;
            const int t = (irow - c) & 63;
            const unsigned g = (unsigned)((SBITS >> t) & 1ull);
            const unsigned bit = 1u << (r * 2 + j);
            if (g) m_gen[i] |= bit;
            if ((c + t >= 5) ? (g != 0) : (t >= 1)) m_t0[i] |= bit;  // terminal rule
            if (g && c <= lrow + r) m_diag[i] |= bit;
          }
        }
      }
    }

    f32x4 o[2][4], ol[2];
#pragma unroll
    for (int i = 0; i < 2; ++i) {
      ol[i] = fzero4();
#pragma unroll
      for (int j = 0; j < 4; ++j) o[i][j] = fzero4();
    }

    STAGE(0, 0);  // prologue: chunk 0 -> buf 0

    for (int kt = 0; kt <= qt; ++kt) {
      f32x4 s[2][2];
#pragma unroll
      for (int i = 0; i < 2; ++i)
#pragma unroll
        for (int j = 0; j < 2; ++j) s[i][j] = fzero4();

      // half 0: compute buf0, stage buf1 (chunk kt*2+1, always exists)
      __syncthreads();
      STAGE(1, kt * 2 + 1);
      QK_HALF(0, 0);

      // half 1: compute buf1, stage buf0 (chunk (kt+1)*2) unless last ktile
      __syncthreads();
      if (kt < qt) STAGE(0, (kt + 1) * 2);
      // V fragments for this wave's 32 keys (global->reg, L2-resident)
      short8 vreg[4];
#pragma unroll
      for (int jd = 0; jd < 4; ++jd)
        vreg[jd] = *(const short8*)(Vt + (size_t)(bh * 64 + jd * 16 + fr) * 2048 +
                                    kt * 64 + wn * 32 + fg * 8);
      QK_HALF(1, 1);

      // ---- no-max softmax: P = exp2(s * scale * log2e), masked -> 0
#pragma unroll
      for (int i = 0; i < 2; ++i) {
        unsigned mm = (kt == 0) ? m_t0[i] : m_gen[i];
        if (kt == qt) mm &= m_diag[i];
#pragma unroll
        for (int r = 0; r < 4; ++r) {
#pragma unroll
          for (int j = 0; j < 2; ++j) {
            float v = s[i][j][r] * 0.18033688f;  // 0.125 * log2(e)
            v = ((mm >> (r * 2 + j)) & 1u) ? v : -1e30f;
            const float pv = __builtin_amdgcn_exp2f(v);
            const int prow = i * 16 + fg * 4 + r;  // prow & 3 == r
            Plds[wid][prow * 32 + ((((j << 1) + (fr >> 3)) ^ r) << 3) + (fr & 7)] =
                f2bf(pv);
          }
        }
      }

      // ---- PV + row-sum (ones column): K=32, one MFMA step per (i,jd)
      __builtin_amdgcn_s_setprio(1);
#pragma unroll
      for (int i = 0; i < 2; ++i) {
        const int arow = i * 16 + fr;
        const short8 pa = *(const short8*)&Plds[wid][arow * 32 + ((fg ^ (fr & 3)) << 3)];
#pragma unroll
        for (int jd = 0; jd < 4; ++jd)
          o[i][jd] = __builtin_amdgcn_mfma_f32_16x16x32_bf16(pa, vreg[jd], o[i][jd], 0, 0, 0);
        ol[i] = __builtin_amdgcn_mfma_f32_16x16x32_bf16(pa, ones, ol[i], 0, 0, 0);
      }
      __builtin_amdgcn_s_setprio(0);
    }

    // ---- combine wn=0 + wn=1 partials via LDS; normalize; write ctx
    __syncthreads();  // all staging drained (vmcnt), Kb free for scratch
    if (wn == 1) {
#pragma unroll
      for (int i = 0; i < 2; ++i) {
#pragma unroll
        for (int r = 0; r < 4; ++r) {
          const int row32 = wm * 32 + i * 16 + fg * 4 + r;
#pragma unroll
          for (int jd = 0; jd < 4; ++jd)
            Osc[row32 * 64 + jd * 16 + fr] = o[i][jd][r];
          if (fr == 0) lsc[row32] = ol[i][r];
        }
      }
    }
    __syncthreads();
    if (wn == 0) {
#pragma unroll
      for (int i = 0; i < 2; ++i) {
#pragma unroll
        for (int r = 0; r < 4; ++r) {
          const int row32 = wm * 32 + i * 16 + fg * 4 + r;
          const float l = ol[i][r] + lsc[row32];
          const float inv = 1.0f / l;
          unsigned short* cp =
              ctx + (size_t)(b * 2048 + qt * 64 + row32) * 512 + h * 64;
#pragma unroll
          for (int jd = 0; jd < 4; ++jd) {
            const float v = o[i][jd][r] + Osc[row32 * 64 + jd * 16 + fr];
            cp[jd * 16 + fr] = f2bf(v * inv);
          }
        }
      }
    }
    __syncthreads();  // scratch reads done before next tile's staging
  }
}

// ---------------------------------------------------------------------------
// Conversions
// ---------------------------------------------------------------------------
__global__ void f32_to_bf16_k(const float* __restrict__ in, unsigned short* __restrict__ out,
                              int n4) {
  const int i = blockIdx.x * 256 + threadIdx.x;
  if (i < n4) {
    const float4 v = ((const float4*)in)[i];
    us4 o;
    o[0] = f2bf(v.x);
    o[1] = f2bf(v.y);
    o[2] = f2bf(v.z);
    o[3] = f2bf(v.w);
    ((us4*)out)[i] = o;
  }
}

// out[n][k] = bf16(in[k][n]) for 512x512 weight (x @ W -> C = A * W^T form)
__global__ void transpose_w_k(const float* __restrict__ in, unsigned short* __restrict__ out) {
  const int idx = blockIdx.x * 256 + threadIdx.x;
  const int row = idx >> 9, col = idx & 511;
  out[idx] = f2bf(in[col * 512 + row]);
}

// ---------------------------------------------------------------------------
extern "C" void kernel_launch(void* const* d_in, const int* in_sizes, int n_in,
                              void* d_out, int out_size, void* d_ws, size_t ws_size,
                              hipStream_t stream) {
  (void)in_sizes; (void)n_in; (void)out_size; (void)ws_size;
  const float* x = (const float*)d_in[0];
  const float* wqk = (const float*)d_in[1];
  const float* wv = (const float*)d_in[2];
  const float* bv = (const float*)d_in[3];
  const float* wp = (const float*)d_in[4];
  const float* bp = (const float*)d_in[5];
  // d_in[6] (mask) unused: mask computed analytically in-kernel.

  char* ws = (char*)d_ws;
  unsigned short* x_bf   = (unsigned short*)(ws + 0);                    //   8 MB [8192][512]
  unsigned short* wqk_bf = (unsigned short*)(ws + (size_t)8 * 1048576);  //   8 MB [8192][512]
  unsigned short* wv_t   = (unsigned short*)(ws + (size_t)16 * 1048576); // 0.5 MB [512][512]
  unsigned short* wp_t   = (unsigned short*)(ws + (size_t)17 * 1048576); // 0.5 MB [512][512]
  unsigned short* qk_bf  = (unsigned short*)(ws + (size_t)18 * 1048576); // 128 MB [8192][8192]
  unsigned short* v_t    = (unsigned short*)(ws + (size_t)146 * 1048576);//   8 MB [2048][2048]
  unsigned short* ctx_bf = (unsigned short*)(ws + (size_t)154 * 1048576);//   8 MB [8192][512]

  f32_to_bf16_k<<<4096, 256, 0, stream>>>(x, x_bf, 1048576);
  f32_to_bf16_k<<<4096, 256, 0, stream>>>(wqk, wqk_bf, 1048576);
  transpose_w_k<<<1024, 256, 0, stream>>>(wv, wv_t);
  transpose_w_k<<<1024, 256, 0, stream>>>(wp, wp_t);

  // QK = x @ w_qk^T : [8192][8192] bf16 (cols 0..4095 = Q, 4096..8191 = K)
  gemm256<<<1024, 512, 0, stream>>>(x_bf, wqk_bf, qk_bf);
  // V = x @ w_v + b_v, stored transposed [ (b*8+h)*64+d ][ t ]
  gemm_bt<1><<<dim3(64, 4), 256, 0, stream>>>(x_bf, wv_t, v_t, bv, 8192, 512, 512);

  flash_attn<<<512, 256, 0, stream>>>(qk_bf, v_t, ctx_bf);

  // out = ctx @ w_proj + b_proj (f32)
  gemm_bt<2><<<dim3(64, 4), 256, 0, stream>>>(ctx_bf, wp_t, d_out, bp, 8192, 512, 512);
}